// Round 9
// baseline (259.263 us; speedup 1.0000x reference)
//
#include <hip/hip_runtime.h>
#include <hip/hip_bf16.h>

// ---------------- problem constants ----------------
#define B_   4
#define T_   2048
#define C_   1024
#define NH_  16
#define HS_  64
#define M_   8192      // B*T
#define N1_  3072      // 3*C
#define BH_  64        // B*NH

typedef __attribute__((ext_vector_type(8))) short short8;   // 8 bf16
typedef __attribute__((ext_vector_type(4))) short short4v;  // 4 bf16
typedef __attribute__((ext_vector_type(4))) float f32x4;

// 1/sqrt(HS) * log2(e) — folded into Q at qkv_gemm epilogue
#define QSCALE 0.18033688011112042f

__device__ __forceinline__ short f2bf(float f) {   // RNE
  unsigned u = __float_as_uint(f);
  unsigned r = (u + 0x7fffu + ((u >> 16) & 1u)) >> 16;
  return (short)r;
}
// packed f32x2 -> bf16x2 (v_cvt_pk_bf16_f32), low word = a
__device__ __forceinline__ unsigned pk_bf16(float a, float b) {
  __hip_bfloat162 h = __float22bfloat162_rn(make_float2(a, b));
  union { __hip_bfloat162 h2; unsigned u; } cv; cv.h2 = h; return cv.u;
}

// async global->LDS, 16B per lane (dest = wave-uniform base + lane*16)
typedef __attribute__((address_space(1))) unsigned int as1_uint;
typedef __attribute__((address_space(3))) unsigned int as3_uint;
__device__ __forceinline__ void g2l16(const void* g, void* l) {
  __builtin_amdgcn_global_load_lds((as1_uint*)g, (as3_uint*)l, 16, 0, 0);
}

// ============================================================
// f32 -> bf16, 8 elements/thread, n % 2048 == 0
// ============================================================
__global__ __launch_bounds__(256) void conv_bf16(
    const float* __restrict__ src, short* __restrict__ dst)
{
  const size_t i = ((size_t)blockIdx.x * 256 + threadIdx.x) * 8;
  const f32x4 a = *(const f32x4*)&src[i];
  const f32x4 b = *(const f32x4*)&src[i + 4];
  short8 o;
  o[0] = f2bf(a[0]); o[1] = f2bf(a[1]); o[2] = f2bf(a[2]); o[3] = f2bf(a[3]);
  o[4] = f2bf(b[0]); o[5] = f2bf(b[1]); o[6] = f2bf(b[2]); o[7] = f2bf(b[3]);
  *(short8*)&dst[i] = o;
}

// ============================================================
// GEMM core (round-7 VERIFIED, reverted from round-8 regression):
// 128x128 tile, 2x2 waves, BK=32, THREE LDS stages (48KB -> 3
// blocks/CU), 2-tile-ahead prefetch with counted vmcnt(4), raw
// s_barrier, zero-conflict swizzle slot(r,c)=4r+(c^((r>>1)&3))
// (linear g2l16 dest + inverse-XOR'd global source + XOR'd reads;
// round-7 counters: SQ_LDS_BANK_CONFLICT 1.887e7 -> 0).
// ============================================================
#define NT_ 32   // K-steps = C_/32

#define GEMM_PRELUDE() \
  const int tid = threadIdx.x; \
  const int lane = tid & 63; \
  const int wid = tid >> 6; \
  const int wy = wid >> 1, wx = wid & 1; \
  const int lq = lane >> 4, lm = lane & 15; \
  const int row0 = blockIdx.x * 128; \
  const int col0 = blockIdx.y * 128; \
  f32x4 acc[4][4] = {}; \
  const int s0 = tid, s1 = tid + 256;            /* slot ids (16B units) */ \
  const int r0 = s0 >> 2, r1 = s1 >> 2;          /* tile row 0..127 */ \
  const int c0s = ((s0 & 3) ^ ((r0 >> 1) & 3)) * 8;  /* src chunk, shorts */ \
  const int c1s = ((s1 & 3) ^ ((r1 >> 1) & 3)) * 8; \
  const int rsw = (lq ^ ((lm >> 1) & 3)) * 8;    /* read swizzle, shorts */

#define GEMM_STAGE(PA, PB, k0, bi) do { \
    g2l16(&PA[(size_t)(row0 + r0) * C_ + (k0) + c0s], &As[bi][s0 * 8]); \
    g2l16(&PA[(size_t)(row0 + r1) * C_ + (k0) + c1s], &As[bi][s1 * 8]); \
    g2l16(&PB[(size_t)(col0 + r0) * C_ + (k0) + c0s], &Bs[bi][s0 * 8]); \
    g2l16(&PB[(size_t)(col0 + r1) * C_ + (k0) + c1s], &Bs[bi][s1 * 8]); \
  } while (0)

#define GEMM_MAINLOOP(PA, PB) \
  GEMM_STAGE(PA, PB, 0, 0); \
  GEMM_STAGE(PA, PB, 32, 1); \
  int cur = 0; \
  for (int t = 0; t < NT_; ++t) { \
    if (t < NT_ - 1) { asm volatile("s_waitcnt vmcnt(4)" ::: "memory"); } \
    else             { asm volatile("s_waitcnt vmcnt(0)" ::: "memory"); } \
    __builtin_amdgcn_sched_barrier(0); \
    __builtin_amdgcn_s_barrier(); \
    __builtin_amdgcn_sched_barrier(0); \
    { \
      const short* Ab = &As[cur][0]; \
      const short* Bb = &Bs[cur][0]; \
      short8 af[4], bfr[4]; \
      _Pragma("unroll") \
      for (int mi = 0; mi < 4; ++mi) \
        af[mi] = *(const short8*)&Ab[(wy * 64 + mi * 16 + lm) * 32 + rsw]; \
      _Pragma("unroll") \
      for (int ni = 0; ni < 4; ++ni) \
        bfr[ni] = *(const short8*)&Bb[(wx * 64 + ni * 16 + lm) * 32 + rsw]; \
      _Pragma("unroll") \
      for (int mi = 0; mi < 4; ++mi) \
        _Pragma("unroll") \
        for (int ni = 0; ni < 4; ++ni) \
          acc[mi][ni] = __builtin_amdgcn_mfma_f32_16x16x32_bf16(af[mi], bfr[ni], acc[mi][ni], 0, 0, 0); \
    } \
    if (t + 2 < NT_) { \
      const int bi2 = (cur + 2) - ((cur + 2) >= 3 ? 3 : 0); \
      GEMM_STAGE(PA, PB, (t + 2) * 32, bi2); \
    } \
    cur = (cur + 1) - ((cur + 1) >= 3 ? 3 : 0); \
  }

// ============================================================
// QKV GEMM (grid = (M/128, 24)): qkv = X @ Wqkv^T + bqkv
// Q pre-scaled by QSCALE (round-4 validated).
// X [M,C] bf16. Q,K -> [BH][T][HS]; V -> TRANSPOSED [BH][HS][T].
// ============================================================
__global__ __launch_bounds__(256) void qkv_gemm(
    const short* __restrict__ X,    // [M, C] bf16
    const short* __restrict__ W,    // [N1, C] bf16
    const float* __restrict__ bias, // [N1] f32
    short* __restrict__ Qo, short* __restrict__ Ko, short* __restrict__ Vt)
{
  __shared__ short As[3][128 * 32];
  __shared__ short Bs[3][128 * 32];
  GEMM_PRELUDE();
  GEMM_MAINLOOP(X, W);

#pragma unroll
  for (int ni = 0; ni < 4; ++ni) {
    const int n = col0 + wx * 64 + ni * 16 + lm;
    const float bv = bias[n];
    const int sel = n >> 10;              // 0=Q, 1=K, 2=V (uniform per tile)
    const int cc = n & (C_ - 1);
    const int h = cc >> 6, d = cc & 63;
    if (sel == 2) {
      // V transposed: Vt[(bh*64 + d)*T + t], 4 consecutive t per lane
#pragma unroll
      for (int mi = 0; mi < 4; ++mi) {
        const int m0 = row0 + wy * 64 + mi * 16 + lq * 4;
        const int b = m0 >> 11, t0 = m0 & (T_ - 1);
        const int bh = b * NH_ + h;
        short4v o;
#pragma unroll
        for (int i = 0; i < 4; ++i) o[i] = f2bf(acc[mi][ni][i] + bv);
        *(short4v*)&Vt[((size_t)bh * HS_ + d) * T_ + t0] = o;
      }
    } else {
      short* dst = (sel == 0) ? Qo : Ko;
      const float qs = (sel == 0) ? QSCALE : 1.0f;
#pragma unroll
      for (int mi = 0; mi < 4; ++mi) {
#pragma unroll
        for (int i = 0; i < 4; ++i) {
          const int m = row0 + wy * 64 + mi * 16 + lq * 4 + i;
          const int b = m >> 11, t = m & (T_ - 1);
          const int bh = b * NH_ + h;
          dst[((size_t)bh * T_ + t) * HS_ + d] = f2bf((acc[mi][ni][i] + bv) * qs);
        }
      }
    }
  }
}

// ============================================================
// Proj GEMM (grid = (M/128, 8)): out = Y @ Wproj^T + bproj -> f32
// ============================================================
__global__ __launch_bounds__(256) void proj_gemm(
    const short* __restrict__ Y,    // [M, C] bf16
    const short* __restrict__ W,    // [C, C] bf16
    const float* __restrict__ bias, // [C] f32
    float* __restrict__ Out)        // [M, C] f32
{
  __shared__ short As[3][128 * 32];
  __shared__ short Bs[3][128 * 32];
  GEMM_PRELUDE();
  GEMM_MAINLOOP(Y, W);

#pragma unroll
  for (int ni = 0; ni < 4; ++ni) {
    const int n = col0 + wx * 64 + ni * 16 + lm;
    const float bv = bias[n];
#pragma unroll
    for (int mi = 0; mi < 4; ++mi) {
#pragma unroll
      for (int i = 0; i < 4; ++i) {
        const int m = row0 + wy * 64 + mi * 16 + lq * 4 + i;
        Out[(size_t)m * C_ + n] = acc[mi][ni][i] + bv;
      }
    }
  }
}

// ============================================================
// Flash attention, round-9: both 4-wave groups work the SAME
// 256-row q-tile (group A = rows 0-127, group B = rows 128-255),
// so group B's kv-need is a 2-tile superset of A's:
// staged iters/bh = sum(4qt+4) = 144 (was 200, -28%), idle
// group-iters = 16/288 = 5.5% (was 32%). Barriers, K/V fetch and
// staging VALU scale down the same 28%. Per-wave math identical to
// the round-6-verified group body; only index arithmetic changed:
// half-A diagonal at kt = 4qt+2grp, half-B at +1, group active
// while kt <= 4qt+2grp+1. Grid (BH, 8) y-major: ty=0 (qt=7,
// longest 32 iters) dispatches first; XCD locality kept (blocks
// sharing bh have linear ids stride 64 -> same XCD).
// FIXED-MAX softmax, QSCALE pre-folded into Q.
// Q,K: [BH][T][HS]; Vt: [BH][HS][T]. Y out bf16 [B][T][C].
// ============================================================
#define LDK 72   // padded LDS row stride (shorts)
__global__ __launch_bounds__(512, 4) void attn(
    const short* __restrict__ Qg, const short* __restrict__ Kg,
    const short* __restrict__ Vg, short* __restrict__ Yo)
{
  __shared__ short Ks[64 * LDK];
  __shared__ short Vs[64 * LDK];

  const int tid = threadIdx.x;
  const int lane = tid & 63;
  const int w = tid >> 6;          // 0..7
  const int wq = w & 3;            // wave within group
  const int grp = w >> 2;          // 0 = rows 0-127 of tile, 1 = rows 128-255
  const int lq = lane >> 4, lm = lane & 15;
  const int bh = blockIdx.x;
  const int b = bh >> 4, h = bh & 15;
  const size_t base = (size_t)bh * T_ * HS_;
  const short* __restrict__ Kb = Kg + base;
  const short* __restrict__ Vb = Vg + base;

  // staging map: 512 threads, one K-row-chunk + one V-row-chunk each
  const int sr = tid >> 3;         // 0..63
  const int sc = (tid & 7) * 8;

  const int qt = 7 - (int)blockIdx.y;       // 256-row q-tile, longest first
  const int nkt = 4 * qt + 4;               // staged kv tiles (group B's need)
  const int hbA = 4 * qt + 2 * grp;         // half-A diagonal kv-tile
  const int hbB = hbA + 1;                  // half-B diagonal = group bound

  const int qA = qt * 256 + grp * 128 + wq * 16 + lm;  // lane's q-row, half A
  const int qB = qA + 64;                              // half B

  // Q fragments (B-layout, pre-scaled)
  const short8 qfA0 = *(const short8*)&Qg[base + (size_t)qA * HS_ + lq * 8];
  const short8 qfA1 = *(const short8*)&Qg[base + (size_t)qA * HS_ + 32 + lq * 8];
  const short8 qfB0 = *(const short8*)&Qg[base + (size_t)qB * HS_ + lq * 8];
  const short8 qfB1 = *(const short8*)&Qg[base + (size_t)qB * HS_ + 32 + lq * 8];

  float lA = 0.0f, lB = 0.0f;               // per-lane partial denominators
  f32x4 oA[4] = {}, oB[4] = {};             // O^T accumulators

  // prefetch tile kt=0
  short8 pk = *(const short8*)&Kb[(size_t)sr * HS_ + sc];
  short8 pv = *(const short8*)&Vb[(size_t)sr * T_ + sc];

#pragma unroll 1
  for (int kt = 0; kt < nkt; ++kt) {
    const int kv0 = kt * 64;

    __syncthreads();   // prior iteration's LDS reads complete
    *(short8*)&Ks[sr * LDK + sc] = pk;
    *(short8*)&Vs[sr * LDK + sc] = pv;
    __syncthreads();   // staging visible

    if (kt + 1 < nkt) {   // prefetch next tile (hidden by compute)
      pk = *(const short8*)&Kb[(size_t)(kv0 + 64 + sr) * HS_ + sc];
      pv = *(const short8*)&Vb[(size_t)sr * T_ + kv0 + 64 + sc];
    }

    if (kt <= hbB) {       // group-active (wave-uniform); grp 0 idles last 2
      const bool doA = (kt <= hbA);   // half A inactive past its diagonal

      // ---- K fragments from LDS, read once, used for both q-halves ----
      short8 kf0[4], kf1[4];
#pragma unroll
      for (int ni = 0; ni < 4; ++ni) {
        kf0[ni] = *(const short8*)&Ks[(ni * 16 + lm) * LDK + lq * 8];
        kf1[ni] = *(const short8*)&Ks[(ni * 16 + lm) * LDK + 32 + lq * 8];
      }

      // ---- S^T = K Q^T for both halves ----
      f32x4 svA[4], svB[4];
      if (doA) {
#pragma unroll
        for (int ni = 0; ni < 4; ++ni) {
          f32x4 s = {};
          s = __builtin_amdgcn_mfma_f32_16x16x32_bf16(kf0[ni], qfA0, s, 0, 0, 0);
          svA[ni] = __builtin_amdgcn_mfma_f32_16x16x32_bf16(kf1[ni], qfA1, s, 0, 0, 0);
        }
      }
#pragma unroll
      for (int ni = 0; ni < 4; ++ni) {
        f32x4 s = {};
        s = __builtin_amdgcn_mfma_f32_16x16x32_bf16(kf0[ni], qfB0, s, 0, 0, 0);
        svB[ni] = __builtin_amdgcn_mfma_f32_16x16x32_bf16(kf1[ni], qfB1, s, 0, 0, 0);
      }

      if (kt == hbA) {          // A diagonal tile
#pragma unroll
        for (int ni = 0; ni < 4; ++ni) {
          const int kvb = kv0 + ni * 16 + lq * 4;
#pragma unroll
          for (int i = 0; i < 4; ++i)
            if (kvb + i > qA) svA[ni][i] = -3.0e38f;
        }
      }
      if (kt == hbB) {          // B diagonal tile
#pragma unroll
        for (int ni = 0; ni < 4; ++ni) {
          const int kvb = kv0 + ni * 16 + lq * 4;
#pragma unroll
          for (int i = 0; i < 4; ++i)
            if (kvb + i > qB) svB[ni][i] = -3.0e38f;
        }
      }

      // ---- fixed-max softmax numerators + packs ----
      short4v p4A[4], p4B[4];
      if (doA) {
#pragma unroll
        for (int ni = 0; ni < 4; ++ni)
#pragma unroll
          for (int i = 0; i < 4; ++i)
            svA[ni][i] = __builtin_amdgcn_exp2f(svA[ni][i]);
        lA += ((svA[0][0] + svA[0][1]) + (svA[0][2] + svA[0][3]))
            + ((svA[1][0] + svA[1][1]) + (svA[1][2] + svA[1][3]))
            + ((svA[2][0] + svA[2][1]) + (svA[2][2] + svA[2][3]))
            + ((svA[3][0] + svA[3][1]) + (svA[3][2] + svA[3][3]));
#pragma unroll
        for (int ni = 0; ni < 4; ++ni) {
          union { short4v s4; unsigned u[2]; } pk2;
          pk2.u[0] = pk_bf16(svA[ni][0], svA[ni][1]);
          pk2.u[1] = pk_bf16(svA[ni][2], svA[ni][3]);
          p4A[ni] = pk2.s4;
        }
      }
#pragma unroll
      for (int ni = 0; ni < 4; ++ni)
#pragma unroll
        for (int i = 0; i < 4; ++i)
          svB[ni][i] = __builtin_amdgcn_exp2f(svB[ni][i]);
      lB += ((svB[0][0] + svB[0][1]) + (svB[0][2] + svB[0][3]))
          + ((svB[1][0] + svB[1][1]) + (svB[1][2] + svB[1][3]))
          + ((svB[2][0] + svB[2][1]) + (svB[2][2] + svB[2][3]))
          + ((svB[3][0] + svB[3][1]) + (svB[3][2] + svB[3][3]));
#pragma unroll
      for (int ni = 0; ni < 4; ++ni) {
        union { short4v s4; unsigned u[2]; } pk2;
        pk2.u[0] = pk_bf16(svB[ni][0], svB[ni][1]);
        pk2.u[1] = pk_bf16(svB[ni][2], svB[ni][3]);
        p4B[ni] = pk2.s4;
      }

      // ---- O^T += V^T P^T: V frags read once, used for both halves ----
      if (doA) {
#pragma unroll
        for (int di = 0; di < 4; ++di) {
#pragma unroll
          for (int ni = 0; ni < 4; ++ni) {
            const short4v vfr = *(const short4v*)&Vs[(di * 16 + lm) * LDK + ni * 16 + lq * 4];
            oA[di] = __builtin_amdgcn_mfma_f32_16x16x16bf16_1k(vfr, p4A[ni], oA[di], 0, 0, 0);
            oB[di] = __builtin_amdgcn_mfma_f32_16x16x16bf16_1k(vfr, p4B[ni], oB[di], 0, 0, 0);
          }
        }
      } else {
#pragma unroll
        for (int di = 0; di < 4; ++di) {
#pragma unroll
          for (int ni = 0; ni < 4; ++ni) {
            const short4v vfr = *(const short4v*)&Vs[(di * 16 + lm) * LDK + ni * 16 + lq * 4];
            oB[di] = __builtin_amdgcn_mfma_f32_16x16x16bf16_1k(vfr, p4B[ni], oB[di], 0, 0, 0);
          }
        }
      }
    }
  }

  // ---- epilogue: reduce l, normalize, store both halves ----
  lA += __shfl_xor(lA, 16);
  lA += __shfl_xor(lA, 32);
  lB += __shfl_xor(lB, 16);
  lB += __shfl_xor(lB, 32);
  const float rlA = 1.0f / lA;
  const float rlB = 1.0f / lB;
  const size_t rowA = ((size_t)(b * T_ + qA)) * C_ + h * HS_;
  const size_t rowB = ((size_t)(b * T_ + qB)) * C_ + h * HS_;
#pragma unroll
  for (int di = 0; di < 4; ++di) {
    union { short4v s4; unsigned u[2]; } pk2;
    pk2.u[0] = pk_bf16(oA[di][0] * rlA, oA[di][1] * rlA);
    pk2.u[1] = pk_bf16(oA[di][2] * rlA, oA[di][3] * rlA);
    *(short4v*)&Yo[rowA + di * 16 + lq * 4] = pk2.s4;
    pk2.u[0] = pk_bf16(oB[di][0] * rlB, oB[di][1] * rlB);
    pk2.u[1] = pk_bf16(oB[di][2] * rlB, oB[di][3] * rlB);
    *(short4v*)&Yo[rowB + di * 16 + lq * 4] = pk2.s4;
  }
}

// ============================================================
extern "C" void kernel_launch(void* const* d_in, const int* in_sizes, int n_in,
                              void* d_out, int out_size, void* d_ws, size_t ws_size,
                              hipStream_t stream) {
  (void)in_sizes; (void)n_in; (void)out_size;
  const float* x     = (const float*)d_in[0];
  const float* Wqkv  = (const float*)d_in[1];
  const float* bqkv  = (const float*)d_in[2];
  const float* Wproj = (const float*)d_in[3];
  const float* bproj = (const float*)d_in[4];
  float* out = (float*)d_out;

  const size_t nWq = (size_t)N1_ * C_;        // 3,145,728
  const size_t nWp = (size_t)C_ * C_;         // 1,048,576
  const size_t nFull = (size_t)M_ * C_;       // 8,388,608
  const size_t nB = (size_t)T_ * C_;          // 2,097,152 per batch

  dim3 blk(256);
  const size_t need_batched = (nWq + nWp + 4 * nFull) * sizeof(short); // 75.6 MB

  if (ws_size >= need_batched) {
    // -------- fully batched pipeline --------
    short* Wq_bf = (short*)d_ws;
    short* Wp_bf = Wq_bf + nWq;
    short* S0    = Wp_bf + nWp;      // x_bf, later Y
    short* Qw    = S0 + nFull;
    short* Kw    = Qw + nFull;
    short* Vw    = Kw + nFull;       // transposed [BH][HS][T]

    conv_bf16<<<dim3((int)(nWq / 2048)), blk, 0, stream>>>(Wqkv, Wq_bf);
    conv_bf16<<<dim3((int)(nWp / 2048)), blk, 0, stream>>>(Wproj, Wp_bf);
    conv_bf16<<<dim3((int)(nFull / 2048)), blk, 0, stream>>>(x, S0);
    qkv_gemm<<<dim3(M_ / 128, N1_ / 128), blk, 0, stream>>>(S0, Wq_bf, bqkv, Qw, Kw, Vw);
    attn<<<dim3(BH_, 8), dim3(512), 0, stream>>>(Qw, Kw, Vw, S0);
    proj_gemm<<<dim3(M_ / 128, C_ / 128), blk, 0, stream>>>(S0, Wp_bf, bproj, out);
  } else {
    // -------- per-batch fallback (25.2 MB ws) --------
    short* Wq_bf = (short*)d_ws;
    short* Wp_bf = Wq_bf + nWq;
    short* S0    = Wp_bf + nWp;      // x_bf, later Y (per batch)
    short* Qw    = S0 + nB;
    short* Kw    = Qw + nB;
    short* Vw    = Kw + nB;

    conv_bf16<<<dim3((int)(nWq / 2048)), blk, 0, stream>>>(Wqkv, Wq_bf);
    conv_bf16<<<dim3((int)(nWp / 2048)), blk, 0, stream>>>(Wproj, Wp_bf);
    for (int b = 0; b < B_; ++b) {
      const float* xb = x   + (size_t)b * nB;
      float*       ob = out + (size_t)b * nB;
      conv_bf16<<<dim3((int)(nB / 2048)), blk, 0, stream>>>(xb, S0);
      qkv_gemm<<<dim3(T_ / 128, N1_ / 128), blk, 0, stream>>>(S0, Wq_bf, bqkv, Qw, Kw, Vw);
      attn<<<dim3(NH_, 8), dim3(512), 0, stream>>>(Qw, Kw, Vw, S0);
      proj_gemm<<<dim3(T_ / 128, C_ / 128), blk, 0, stream>>>(S0, Wp_bf, bproj, ob);
    }
  }
}

// Round 10
// 245.498 us; speedup vs baseline: 1.0561x; 1.0561x over previous
//
#include <hip/hip_runtime.h>
#include <hip/hip_bf16.h>

// ---------------- problem constants ----------------
#define B_   4
#define T_   2048
#define C_   1024
#define NH_  16
#define HS_  64
#define M_   8192      // B*T
#define N1_  3072      // 3*C
#define BH_  64        // B*NH

typedef __attribute__((ext_vector_type(8))) short short8;   // 8 bf16
typedef __attribute__((ext_vector_type(4))) short short4v;  // 4 bf16
typedef __attribute__((ext_vector_type(4))) float f32x4;

// 1/sqrt(HS) * log2(e) — folded into Q at qkv_gemm epilogue
#define QSCALE 0.18033688011112042f

__device__ __forceinline__ short f2bf(float f) {   // RNE
  unsigned u = __float_as_uint(f);
  unsigned r = (u + 0x7fffu + ((u >> 16) & 1u)) >> 16;
  return (short)r;
}
// packed f32x2 -> bf16x2 (v_cvt_pk_bf16_f32), low word = a
__device__ __forceinline__ unsigned pk_bf16(float a, float b) {
  __hip_bfloat162 h = __float22bfloat162_rn(make_float2(a, b));
  union { __hip_bfloat162 h2; unsigned u; } cv; cv.h2 = h; return cv.u;
}

// async global->LDS, 16B per lane (dest = wave-uniform base + lane*16)
typedef __attribute__((address_space(1))) unsigned int as1_uint;
typedef __attribute__((address_space(3))) unsigned int as3_uint;
__device__ __forceinline__ void g2l16(const void* g, void* l) {
  __builtin_amdgcn_global_load_lds((as1_uint*)g, (as3_uint*)l, 16, 0, 0);
}

// ============================================================
// f32 -> bf16, 8 elements/thread, n % 2048 == 0
// ============================================================
__device__ __forceinline__ void conv_body(
    const float* __restrict__ src, short* __restrict__ dst, int blk)
{
  const size_t i = ((size_t)blk * 256 + threadIdx.x) * 8;
  const f32x4 a = *(const f32x4*)&src[i];
  const f32x4 b = *(const f32x4*)&src[i + 4];
  short8 o;
  o[0] = f2bf(a[0]); o[1] = f2bf(a[1]); o[2] = f2bf(a[2]); o[3] = f2bf(a[3]);
  o[4] = f2bf(b[0]); o[5] = f2bf(b[1]); o[6] = f2bf(b[2]); o[7] = f2bf(b[3]);
  *(short8*)&dst[i] = o;
}

__global__ __launch_bounds__(256) void conv_bf16(
    const float* __restrict__ src, short* __restrict__ dst)
{
  conv_body(src, dst, (int)blockIdx.x);
}

// fused: Wqkv (1536 blks) | Wproj (512 blks) | x (4096 blks) in ONE
// launch — removes 2 launch/drain gaps (round-10: pure overhead cut).
__global__ __launch_bounds__(256) void conv_bf16_fused(
    const float* __restrict__ sWq, short* __restrict__ dWq,
    const float* __restrict__ sWp, short* __restrict__ dWp,
    const float* __restrict__ sX,  short* __restrict__ dX)
{
  const int bx = (int)blockIdx.x;
  if (bx < 1536)       conv_body(sWq, dWq, bx);
  else if (bx < 2048)  conv_body(sWp, dWp, bx - 1536);
  else                 conv_body(sX,  dX,  bx - 2048);
}

// ============================================================
// GEMM core (round-7 VERIFIED; best total 248.2): 128x128 tile,
// 2x2 waves, BK=32, THREE LDS stages (48KB -> 3 blocks/CU),
// 2-tile-ahead prefetch with counted vmcnt(4), raw s_barrier,
// zero-conflict swizzle slot(r,c)=4r+(c^((r>>1)&3)) (linear g2l16
// dest + inverse-XOR'd global source + XOR'd reads; verified:
// SQ_LDS_BANK_CONFLICT 1.887e7 -> 0).
// Round-8's 128x256 variant regressed (occupancy 15%): reverted.
// ============================================================
#define NT_ 32   // K-steps = C_/32

#define GEMM_PRELUDE() \
  const int tid = threadIdx.x; \
  const int lane = tid & 63; \
  const int wid = tid >> 6; \
  const int wy = wid >> 1, wx = wid & 1; \
  const int lq = lane >> 4, lm = lane & 15; \
  const int row0 = blockIdx.x * 128; \
  const int col0 = blockIdx.y * 128; \
  f32x4 acc[4][4] = {}; \
  const int s0 = tid, s1 = tid + 256;            /* slot ids (16B units) */ \
  const int r0 = s0 >> 2, r1 = s1 >> 2;          /* tile row 0..127 */ \
  const int c0s = ((s0 & 3) ^ ((r0 >> 1) & 3)) * 8;  /* src chunk, shorts */ \
  const int c1s = ((s1 & 3) ^ ((r1 >> 1) & 3)) * 8; \
  const int rsw = (lq ^ ((lm >> 1) & 3)) * 8;    /* read swizzle, shorts */

#define GEMM_STAGE(PA, PB, k0, bi) do { \
    g2l16(&PA[(size_t)(row0 + r0) * C_ + (k0) + c0s], &As[bi][s0 * 8]); \
    g2l16(&PA[(size_t)(row0 + r1) * C_ + (k0) + c1s], &As[bi][s1 * 8]); \
    g2l16(&PB[(size_t)(col0 + r0) * C_ + (k0) + c0s], &Bs[bi][s0 * 8]); \
    g2l16(&PB[(size_t)(col0 + r1) * C_ + (k0) + c1s], &Bs[bi][s1 * 8]); \
  } while (0)

#define GEMM_MAINLOOP(PA, PB) \
  GEMM_STAGE(PA, PB, 0, 0); \
  GEMM_STAGE(PA, PB, 32, 1); \
  int cur = 0; \
  for (int t = 0; t < NT_; ++t) { \
    if (t < NT_ - 1) { asm volatile("s_waitcnt vmcnt(4)" ::: "memory"); } \
    else             { asm volatile("s_waitcnt vmcnt(0)" ::: "memory"); } \
    __builtin_amdgcn_sched_barrier(0); \
    __builtin_amdgcn_s_barrier(); \
    __builtin_amdgcn_sched_barrier(0); \
    { \
      const short* Ab = &As[cur][0]; \
      const short* Bb = &Bs[cur][0]; \
      short8 af[4], bfr[4]; \
      _Pragma("unroll") \
      for (int mi = 0; mi < 4; ++mi) \
        af[mi] = *(const short8*)&Ab[(wy * 64 + mi * 16 + lm) * 32 + rsw]; \
      _Pragma("unroll") \
      for (int ni = 0; ni < 4; ++ni) \
        bfr[ni] = *(const short8*)&Bb[(wx * 64 + ni * 16 + lm) * 32 + rsw]; \
      _Pragma("unroll") \
      for (int mi = 0; mi < 4; ++mi) \
        _Pragma("unroll") \
        for (int ni = 0; ni < 4; ++ni) \
          acc[mi][ni] = __builtin_amdgcn_mfma_f32_16x16x32_bf16(af[mi], bfr[ni], acc[mi][ni], 0, 0, 0); \
    } \
    if (t + 2 < NT_) { \
      const int bi2 = (cur + 2) - ((cur + 2) >= 3 ? 3 : 0); \
      GEMM_STAGE(PA, PB, (t + 2) * 32, bi2); \
    } \
    cur = (cur + 1) - ((cur + 1) >= 3 ? 3 : 0); \
  }

// ============================================================
// QKV GEMM (grid = (M/128, 24)): qkv = X @ Wqkv^T + bqkv
// Q pre-scaled by QSCALE (round-4 validated).
// X [M,C] bf16. Q,K -> [BH][T][HS]; V -> TRANSPOSED [BH][HS][T].
// ============================================================
__global__ __launch_bounds__(256) void qkv_gemm(
    const short* __restrict__ X,    // [M, C] bf16
    const short* __restrict__ W,    // [N1, C] bf16
    const float* __restrict__ bias, // [N1] f32
    short* __restrict__ Qo, short* __restrict__ Ko, short* __restrict__ Vt)
{
  __shared__ short As[3][128 * 32];
  __shared__ short Bs[3][128 * 32];
  GEMM_PRELUDE();
  GEMM_MAINLOOP(X, W);

#pragma unroll
  for (int ni = 0; ni < 4; ++ni) {
    const int n = col0 + wx * 64 + ni * 16 + lm;
    const float bv = bias[n];
    const int sel = n >> 10;              // 0=Q, 1=K, 2=V (uniform per tile)
    const int cc = n & (C_ - 1);
    const int h = cc >> 6, d = cc & 63;
    if (sel == 2) {
      // V transposed: Vt[(bh*64 + d)*T + t], 4 consecutive t per lane
#pragma unroll
      for (int mi = 0; mi < 4; ++mi) {
        const int m0 = row0 + wy * 64 + mi * 16 + lq * 4;
        const int b = m0 >> 11, t0 = m0 & (T_ - 1);
        const int bh = b * NH_ + h;
        short4v o;
#pragma unroll
        for (int i = 0; i < 4; ++i) o[i] = f2bf(acc[mi][ni][i] + bv);
        *(short4v*)&Vt[((size_t)bh * HS_ + d) * T_ + t0] = o;
      }
    } else {
      short* dst = (sel == 0) ? Qo : Ko;
      const float qs = (sel == 0) ? QSCALE : 1.0f;
#pragma unroll
      for (int mi = 0; mi < 4; ++mi) {
#pragma unroll
        for (int i = 0; i < 4; ++i) {
          const int m = row0 + wy * 64 + mi * 16 + lq * 4 + i;
          const int b = m >> 11, t = m & (T_ - 1);
          const int bh = b * NH_ + h;
          dst[((size_t)bh * T_ + t) * HS_ + d] = f2bf((acc[mi][ni][i] + bv) * qs);
        }
      }
    }
  }
}

// ============================================================
// Proj GEMM (grid = (M/128, 8)): out = Y @ Wproj^T + bproj -> f32
// ============================================================
__global__ __launch_bounds__(256) void proj_gemm(
    const short* __restrict__ Y,    // [M, C] bf16
    const short* __restrict__ W,    // [C, C] bf16
    const float* __restrict__ bias, // [C] f32
    float* __restrict__ Out)        // [M, C] f32
{
  __shared__ short As[3][128 * 32];
  __shared__ short Bs[3][128 * 32];
  GEMM_PRELUDE();
  GEMM_MAINLOOP(Y, W);

#pragma unroll
  for (int ni = 0; ni < 4; ++ni) {
    const int n = col0 + wx * 64 + ni * 16 + lm;
    const float bv = bias[n];
#pragma unroll
    for (int mi = 0; mi < 4; ++mi) {
#pragma unroll
      for (int i = 0; i < 4; ++i) {
        const int m = row0 + wy * 64 + mi * 16 + lq * 4 + i;
        Out[(size_t)m * C_ + n] = acc[mi][ni][i] + bv;
      }
    }
  }
}

// ============================================================
// Flash attention (round-6/7 VERIFIED at 72.0us, restored after the
// round-9 same-tile variant regressed to 83.7: in an all-resident
// grid, per-block BALANCE beats aggregate-work minimization — the
// (15-ty, ty) pairing keeps every block at ~34 useful group-iters so
// co-resident blocks fill each other's stalls to the end).
// 512 threads = two 4-wave groups sharing one K/V staging; group A
// tile 15-ty, group B tile ty, concurrent over one kv loop of
// 32-2ty iters. Grid (BH, 8) for XCD locality (FETCH 147->27MB).
// FIXED-MAX softmax, QSCALE pre-folded into Q.
// Q,K: [BH][T][HS]; Vt: [BH][HS][T]. Y out bf16 [B][T][C].
// ============================================================
#define LDK 72   // padded LDS row stride (shorts)
__global__ __launch_bounds__(512, 4) void attn(
    const short* __restrict__ Qg, const short* __restrict__ Kg,
    const short* __restrict__ Vg, short* __restrict__ Yo)
{
  __shared__ short Ks[64 * LDK];
  __shared__ short Vs[64 * LDK];

  const int tid = threadIdx.x;
  const int lane = tid & 63;
  const int w = tid >> 6;          // 0..7
  const int wq = w & 3;            // wave within group
  const int grp = w >> 2;          // 0 = group A (long tile), 1 = group B
  const int lq = lane >> 4, lm = lane & 15;
  const int bh = blockIdx.x;
  const int b = bh >> 4, h = bh & 15;
  const size_t base = (size_t)bh * T_ * HS_;
  const short* __restrict__ Kb = Kg + base;
  const short* __restrict__ Vb = Vg + base;

  // staging map: 512 threads, one K-row-chunk + one V-row-chunk each
  const int sr = tid >> 3;         // 0..63
  const int sc = (tid & 7) * 8;

  const int ty = blockIdx.y;                // 0..7
  const int qt = grp ? ty : (15 - ty);      // this group's 128-row q-tile
  const int nkt_g = 2 * qt + 2;             // this group's kv-tile count
  const int nktA = 32 - 2 * ty;             // loop bound (group A, longest)

  const int qA = qt * 128 + wq * 16 + lm;   // lane's q-row, half A
  const int qB = qA + 64;                   // half B

  // Q fragments (B-layout, pre-scaled)
  const short8 qfA0 = *(const short8*)&Qg[base + (size_t)qA * HS_ + lq * 8];
  const short8 qfA1 = *(const short8*)&Qg[base + (size_t)qA * HS_ + 32 + lq * 8];
  const short8 qfB0 = *(const short8*)&Qg[base + (size_t)qB * HS_ + lq * 8];
  const short8 qfB1 = *(const short8*)&Qg[base + (size_t)qB * HS_ + 32 + lq * 8];

  float lA = 0.0f, lB = 0.0f;               // per-lane partial denominators
  f32x4 oA[4] = {}, oB[4] = {};             // O^T accumulators

  // prefetch tile kt=0
  short8 pk = *(const short8*)&Kb[(size_t)sr * HS_ + sc];
  short8 pv = *(const short8*)&Vb[(size_t)sr * T_ + sc];

#pragma unroll 1
  for (int kt = 0; kt < nktA; ++kt) {
    const int kv0 = kt * 64;

    __syncthreads();   // prior iteration's LDS reads complete
    *(short8*)&Ks[sr * LDK + sc] = pk;
    *(short8*)&Vs[sr * LDK + sc] = pv;
    __syncthreads();   // staging visible

    if (kt + 1 < nktA) {   // prefetch next tile (hidden by compute)
      pk = *(const short8*)&Kb[(size_t)(kv0 + 64 + sr) * HS_ + sc];
      pv = *(const short8*)&Vb[(size_t)sr * T_ + kv0 + 64 + sc];
    }

    if (kt < nkt_g) {      // group-active (wave-uniform)
      const bool doA = (kt <= 2 * qt);   // A-half inactive only on last tile

      // ---- K fragments from LDS, read once, used for both q-halves ----
      short8 kf0[4], kf1[4];
#pragma unroll
      for (int ni = 0; ni < 4; ++ni) {
        kf0[ni] = *(const short8*)&Ks[(ni * 16 + lm) * LDK + lq * 8];
        kf1[ni] = *(const short8*)&Ks[(ni * 16 + lm) * LDK + 32 + lq * 8];
      }

      // ---- S^T = K Q^T for both halves ----
      f32x4 svA[4], svB[4];
      if (doA) {
#pragma unroll
        for (int ni = 0; ni < 4; ++ni) {
          f32x4 s = {};
          s = __builtin_amdgcn_mfma_f32_16x16x32_bf16(kf0[ni], qfA0, s, 0, 0, 0);
          svA[ni] = __builtin_amdgcn_mfma_f32_16x16x32_bf16(kf1[ni], qfA1, s, 0, 0, 0);
        }
      }
#pragma unroll
      for (int ni = 0; ni < 4; ++ni) {
        f32x4 s = {};
        s = __builtin_amdgcn_mfma_f32_16x16x32_bf16(kf0[ni], qfB0, s, 0, 0, 0);
        svB[ni] = __builtin_amdgcn_mfma_f32_16x16x32_bf16(kf1[ni], qfB1, s, 0, 0, 0);
      }

      if (kt == 2 * qt) {       // A diagonal tile
#pragma unroll
        for (int ni = 0; ni < 4; ++ni) {
          const int kvb = kv0 + ni * 16 + lq * 4;
#pragma unroll
          for (int i = 0; i < 4; ++i)
            if (kvb + i > qA) svA[ni][i] = -3.0e38f;
        }
      }
      if (kt == 2 * qt + 1) {   // B diagonal tile
#pragma unroll
        for (int ni = 0; ni < 4; ++ni) {
          const int kvb = kv0 + ni * 16 + lq * 4;
#pragma unroll
          for (int i = 0; i < 4; ++i)
            if (kvb + i > qB) svB[ni][i] = -3.0e38f;
        }
      }

      // ---- fixed-max softmax numerators + packs ----
      short4v p4A[4], p4B[4];
      if (doA) {
#pragma unroll
        for (int ni = 0; ni < 4; ++ni)
#pragma unroll
          for (int i = 0; i < 4; ++i)
            svA[ni][i] = __builtin_amdgcn_exp2f(svA[ni][i]);
        lA += ((svA[0][0] + svA[0][1]) + (svA[0][2] + svA[0][3]))
            + ((svA[1][0] + svA[1][1]) + (svA[1][2] + svA[1][3]))
            + ((svA[2][0] + svA[2][1]) + (svA[2][2] + svA[2][3]))
            + ((svA[3][0] + svA[3][1]) + (svA[3][2] + svA[3][3]));
#pragma unroll
        for (int ni = 0; ni < 4; ++ni) {
          union { short4v s4; unsigned u[2]; } pk2;
          pk2.u[0] = pk_bf16(svA[ni][0], svA[ni][1]);
          pk2.u[1] = pk_bf16(svA[ni][2], svA[ni][3]);
          p4A[ni] = pk2.s4;
        }
      }
#pragma unroll
      for (int ni = 0; ni < 4; ++ni)
#pragma unroll
        for (int i = 0; i < 4; ++i)
          svB[ni][i] = __builtin_amdgcn_exp2f(svB[ni][i]);
      lB += ((svB[0][0] + svB[0][1]) + (svB[0][2] + svB[0][3]))
          + ((svB[1][0] + svB[1][1]) + (svB[1][2] + svB[1][3]))
          + ((svB[2][0] + svB[2][1]) + (svB[2][2] + svB[2][3]))
          + ((svB[3][0] + svB[3][1]) + (svB[3][2] + svB[3][3]));
#pragma unroll
      for (int ni = 0; ni < 4; ++ni) {
        union { short4v s4; unsigned u[2]; } pk2;
        pk2.u[0] = pk_bf16(svB[ni][0], svB[ni][1]);
        pk2.u[1] = pk_bf16(svB[ni][2], svB[ni][3]);
        p4B[ni] = pk2.s4;
      }

      // ---- O^T += V^T P^T: V frags read once, used for both halves ----
      if (doA) {
#pragma unroll
        for (int di = 0; di < 4; ++di) {
#pragma unroll
          for (int ni = 0; ni < 4; ++ni) {
            const short4v vfr = *(const short4v*)&Vs[(di * 16 + lm) * LDK + ni * 16 + lq * 4];
            oA[di] = __builtin_amdgcn_mfma_f32_16x16x16bf16_1k(vfr, p4A[ni], oA[di], 0, 0, 0);
            oB[di] = __builtin_amdgcn_mfma_f32_16x16x16bf16_1k(vfr, p4B[ni], oB[di], 0, 0, 0);
          }
        }
      } else {
#pragma unroll
        for (int di = 0; di < 4; ++di) {
#pragma unroll
          for (int ni = 0; ni < 4; ++ni) {
            const short4v vfr = *(const short4v*)&Vs[(di * 16 + lm) * LDK + ni * 16 + lq * 4];
            oB[di] = __builtin_amdgcn_mfma_f32_16x16x16bf16_1k(vfr, p4B[ni], oB[di], 0, 0, 0);
          }
        }
      }
    }
  }

  // ---- epilogue: reduce l, normalize, store both halves ----
  lA += __shfl_xor(lA, 16);
  lA += __shfl_xor(lA, 32);
  lB += __shfl_xor(lB, 16);
  lB += __shfl_xor(lB, 32);
  const float rlA = 1.0f / lA;
  const float rlB = 1.0f / lB;
  const size_t rowA = ((size_t)(b * T_ + qA)) * C_ + h * HS_;
  const size_t rowB = ((size_t)(b * T_ + qB)) * C_ + h * HS_;
#pragma unroll
  for (int di = 0; di < 4; ++di) {
    union { short4v s4; unsigned u[2]; } pk2;
    pk2.u[0] = pk_bf16(oA[di][0] * rlA, oA[di][1] * rlA);
    pk2.u[1] = pk_bf16(oA[di][2] * rlA, oA[di][3] * rlA);
    *(short4v*)&Yo[rowA + di * 16 + lq * 4] = pk2.s4;
    pk2.u[0] = pk_bf16(oB[di][0] * rlB, oB[di][1] * rlB);
    pk2.u[1] = pk_bf16(oB[di][2] * rlB, oB[di][3] * rlB);
    *(short4v*)&Yo[rowB + di * 16 + lq * 4] = pk2.s4;
  }
}

// ============================================================
extern "C" void kernel_launch(void* const* d_in, const int* in_sizes, int n_in,
                              void* d_out, int out_size, void* d_ws, size_t ws_size,
                              hipStream_t stream) {
  (void)in_sizes; (void)n_in; (void)out_size;
  const float* x     = (const float*)d_in[0];
  const float* Wqkv  = (const float*)d_in[1];
  const float* bqkv  = (const float*)d_in[2];
  const float* Wproj = (const float*)d_in[3];
  const float* bproj = (const float*)d_in[4];
  float* out = (float*)d_out;

  const size_t nWq = (size_t)N1_ * C_;        // 3,145,728
  const size_t nWp = (size_t)C_ * C_;         // 1,048,576
  const size_t nFull = (size_t)M_ * C_;       // 8,388,608
  const size_t nB = (size_t)T_ * C_;          // 2,097,152 per batch

  dim3 blk(256);
  const size_t need_batched = (nWq + nWp + 4 * nFull) * sizeof(short); // 75.6 MB

  if (ws_size >= need_batched) {
    // -------- fully batched pipeline --------
    short* Wq_bf = (short*)d_ws;
    short* Wp_bf = Wq_bf + nWq;
    short* S0    = Wp_bf + nWp;      // x_bf, later Y
    short* Qw    = S0 + nFull;
    short* Kw    = Qw + nFull;
    short* Vw    = Kw + nFull;       // transposed [BH][HS][T]

    conv_bf16_fused<<<dim3(6144), blk, 0, stream>>>(Wqkv, Wq_bf, Wproj, Wp_bf, x, S0);
    qkv_gemm<<<dim3(M_ / 128, N1_ / 128), blk, 0, stream>>>(S0, Wq_bf, bqkv, Qw, Kw, Vw);
    attn<<<dim3(BH_, 8), dim3(512), 0, stream>>>(Qw, Kw, Vw, S0);
    proj_gemm<<<dim3(M_ / 128, C_ / 128), blk, 0, stream>>>(S0, Wp_bf, bproj, out);
  } else {
    // -------- per-batch fallback (25.2 MB ws) --------
    short* Wq_bf = (short*)d_ws;
    short* Wp_bf = Wq_bf + nWq;
    short* S0    = Wp_bf + nWp;      // x_bf, later Y (per batch)
    short* Qw    = S0 + nB;
    short* Kw    = Qw + nB;
    short* Vw    = Kw + nB;

    conv_bf16<<<dim3((int)(nWq / 2048)), blk, 0, stream>>>(Wqkv, Wq_bf);
    conv_bf16<<<dim3((int)(nWp / 2048)), blk, 0, stream>>>(Wproj, Wp_bf);
    for (int b = 0; b < B_; ++b) {
      const float* xb = x   + (size_t)b * nB;
      float*       ob = out + (size_t)b * nB;
      conv_bf16<<<dim3((int)(nB / 2048)), blk, 0, stream>>>(xb, S0);
      qkv_gemm<<<dim3(T_ / 128, N1_ / 128), blk, 0, stream>>>(S0, Wq_bf, bqkv, Qw, Kw, Vw);
      attn<<<dim3(NH_, 8), dim3(512), 0, stream>>>(Qw, Kw, Vw, S0);
      proj_gemm<<<dim3(T_ / 128, C_ / 128), blk, 0, stream>>>(S0, Wp_bf, bproj, ob);
    }
  }
}